// Round 7
// baseline (1220.425 us; speedup 1.0000x reference)
//
#include <hip/hip_runtime.h>

typedef unsigned short ushort_t;
typedef __bf16 v8bf __attribute__((ext_vector_type(8)));
typedef float v4f __attribute__((ext_vector_type(4)));

#define B_ 32
#define N_ 1024
#define C_ 768
#define G_ 8
#define HD_ 96
#define CH_ 3072
#define M_ 32768  // B*N

static __device__ __forceinline__ float b2f(ushort_t u) {
    union { float f; unsigned int i; } z; z.i = ((unsigned int)u) << 16; return z.f;
}
static __device__ __forceinline__ ushort_t f2b(float f) {
    unsigned int u = __float_as_uint(f);
    u += 0x7fff + ((u >> 16) & 1);   // RNE
    return (ushort_t)(u >> 16);
}
static __device__ __forceinline__ unsigned int pk2(float a, float b) {
    return (unsigned int)f2b(a) | ((unsigned int)f2b(b) << 16);
}

#define GLOAD_LDS16(g, l) __builtin_amdgcn_global_load_lds( \
    (const __attribute__((address_space(1))) unsigned int*)(g), \
    (__attribute__((address_space(3))) unsigned int*)(l), 16, 0, 0)

// ---------------- fp32 -> bf16 weight conversion, all 4 weights in 1 launch ---
__global__ __launch_bounds__(256) void cvt_all(
    const float* __restrict__ a, const float* __restrict__ b,
    const float* __restrict__ c, const float* __restrict__ d,
    ushort_t* __restrict__ o)
{
    int blk = blockIdx.x;            // 6912 total
    const float* src; ushort_t* dst; int off;
    if (blk < 1728)      { src = a; dst = o;                          off = blk; }
    else if (blk < 2304) { src = b; dst = o + 2304 * 768;             off = blk - 1728; }
    else if (blk < 4608) { src = c; dst = o + 2304 * 768 + 768 * 768; off = blk - 2304; }
    else                 { src = d; dst = o + 2304 * 768 + 768 * 768 + 3072 * 768; off = blk - 4608; }
    int i = (off * 256 + threadIdx.x) * 4;
    float4 v = *(const float4*)(src + i);
    uint2 p; p.x = pk2(v.x, v.y); p.y = pk2(v.z, v.w);
    *(uint2*)(dst + i) = p;
}

// ---------------- dwconv weight transpose: [C,3,3] -> [9][C] fp32, both -------
__global__ __launch_bounds__(256) void transpose_w2(
    const float* __restrict__ w1, const float* __restrict__ w2,
    float* __restrict__ wt1, float* __restrict__ wt2)
{
    int blk = blockIdx.x;            // 54
    const float* w = (blk < 27) ? w1 : w2;
    float* wt = (blk < 27) ? wt1 : wt2;
    int i = (blk % 27) * 256 + threadIdx.x;
    int c = i / 9, k = i % 9;
    wt[k * C_ + c] = w[i];
}

// ---------------- depthwise 3x3 conv + residual (fp32): out = x + conv(x) ----
__global__ __launch_bounds__(256) void dwconv_add(
    const float* __restrict__ xin, const float* __restrict__ wt,
    const float* __restrict__ bias, float* __restrict__ out)
{
    int t = threadIdx.x;
    int bid = blockIdx.x;
    int cblk = bid % 6;                  // 6 = 768/128
    int bh = bid / 6;                    // b*32 + h
    int b = bh >> 5, h = bh & 31;
    int tw = t >> 5;                     // 0..7  -> 4-pixel group
    int c0 = cblk * 128 + (t & 31) * 4;  // channel base (float4)
    int w0 = tw * 4;

    float4 tap[3][6];
#pragma unroll
    for (int dh = 0; dh < 3; dh++) {
        int hh = h + dh - 1;
        bool hok = (hh >= 0) && (hh < 32);   // block-uniform branch
#pragma unroll
        for (int dw = 0; dw < 6; dw++) {
            int ww = w0 + dw - 1;
            bool ok = hok && (ww >= 0) && (ww < 32);
            if (ok)
                tap[dh][dw] = *(const float4*)(
                    xin + (size_t)((b << 10) | (hh << 5) | ww) * C_ + c0);
            else
                tap[dh][dw] = make_float4(0.f, 0.f, 0.f, 0.f);
        }
    }
    float4 wv[9];
#pragma unroll
    for (int k = 0; k < 9; k++)
        wv[k] = *(const float4*)(wt + k * C_ + c0);
    float4 bv = *(const float4*)(bias + c0);

#pragma unroll
    for (int i = 0; i < 4; i++) {
        float4 acc = bv;
#pragma unroll
        for (int dh = 0; dh < 3; dh++)
#pragma unroll
            for (int dw = 0; dw < 3; dw++) {
                float4 xv = tap[dh][i + dw];
                float4 wk = wv[dh * 3 + dw];
                acc.x += wk.x * xv.x; acc.y += wk.y * xv.y;
                acc.z += wk.z * xv.z; acc.w += wk.w * xv.w;
            }
        float4 xr = tap[1][i + 1];
        acc.x += xr.x; acc.y += xr.y; acc.z += xr.z; acc.w += xr.w;
        *(float4*)(out + (size_t)((b << 10) | (h << 5) | (w0 + i)) * C_ + c0) = acc;
    }
}

// ---------------- layernorm over C=768: fp32 in -> bf16 out -------------------
__global__ __launch_bounds__(256) void layernorm_bf(
    const float* __restrict__ xin, const float* __restrict__ g,
    const float* __restrict__ bb, ushort_t* __restrict__ out)
{
    int row = blockIdx.x;
    int t = threadIdx.x;
    const float* xr = xin + (size_t)row * C_;
    float x0 = xr[t], x1 = xr[t + 256], x2 = xr[t + 512];
    float s1 = x0 + x1 + x2;
    float s2 = x0 * x0 + x1 * x1 + x2 * x2;
#pragma unroll
    for (int o = 32; o > 0; o >>= 1) {
        s1 += __shfl_xor(s1, o);
        s2 += __shfl_xor(s2, o);
    }
    __shared__ float red[8];
    if ((t & 63) == 0) { red[(t >> 6) * 2] = s1; red[(t >> 6) * 2 + 1] = s2; }
    __syncthreads();
    s1 = red[0] + red[2] + red[4] + red[6];
    s2 = red[1] + red[3] + red[5] + red[7];
    float m = s1 * (1.0f / 768.0f);
    float var = s2 * (1.0f / 768.0f) - m * m;
    float inv = rsqrtf(var + 1e-5f);
    ushort_t* orow = out + (size_t)row * C_;
    orow[t]       = f2b((x0 - m) * inv * g[t]       + bb[t]);
    orow[t + 256] = f2b((x1 - m) * inv * g[t + 256] + bb[t + 256]);
    orow[t + 512] = f2b((x2 - m) * inv * g[t + 512] + bb[t + 512]);
}

// ---------------- bf16 GEMM: 128x128, ring-3, counted vmcnt, T2 swizzle -------
// (R4 known-good: fc2 146us, conflicts 0)
template <int EPI>
__global__ __launch_bounds__(256) void gemm_bt(
    const ushort_t* __restrict__ A, const ushort_t* __restrict__ W,
    const float* __restrict__ bias, const float* __restrict__ resid,
    void* __restrict__ outv, int M, int Nf, int K)
{
    __shared__ __align__(16) ushort_t ring[3][2][128 * 32];  // 48 KB
    int t = threadIdx.x;
    int bm = blockIdx.x;   // M/128
    int bn = blockIdx.y;   // Nf/128
    int wave = t >> 6, lane = t & 63;
    int wm = (wave >> 1) * 64;
    int wn = (wave & 1) * 64;
    int row16 = lane & 15;
    int quad = lane >> 4;
    int qswz = (quad * 8) ^ (((row16 >> 1) & 3) * 8);  // read-side swizzle

    int r0 = wave * 16 + (lane >> 2);
    int r1 = (wave + 4) * 16 + (lane >> 2);
    int c8s = ((lane & 3) ^ ((lane >> 3) & 3)) * 8;
    const ushort_t* Ag0 = A + (size_t)(bm * 128 + r0) * K + c8s;
    const ushort_t* Ag1 = A + (size_t)(bm * 128 + r1) * K + c8s;
    const ushort_t* Wg0 = W + (size_t)(bn * 128 + r0) * K + c8s;
    const ushort_t* Wg1 = W + (size_t)(bn * 128 + r1) * K + c8s;

    v4f acc[4][4];
#pragma unroll
    for (int i = 0; i < 4; i++)
#pragma unroll
        for (int j = 0; j < 4; j++) acc[i][j] = (v4f){0.f, 0.f, 0.f, 0.f};

    const int NT = K >> 5;   // K-tiles of 32

    auto STAGE = [&](int kt) {
        int s = kt % 3;
        ushort_t* a = &ring[s][0][0];
        ushort_t* b = &ring[s][1][0];
        int off = kt * 32;
        GLOAD_LDS16(Ag0 + off, a + wave * 512);
        GLOAD_LDS16(Ag1 + off, a + (wave + 4) * 512);
        GLOAD_LDS16(Wg0 + off, b + wave * 512);
        GLOAD_LDS16(Wg1 + off, b + (wave + 4) * 512);
    };

    STAGE(0);
    STAGE(1);
    asm volatile("s_waitcnt vmcnt(4)" ::: "memory");
    __builtin_amdgcn_s_barrier();

    for (int kt = 0; kt < NT; ++kt) {
        if (kt + 2 < NT) STAGE(kt + 2);          // into slot freed at kt-1

        const ushort_t* sA = &ring[kt % 3][0][0];
        const ushort_t* sB = &ring[kt % 3][1][0];
        v8bf af[4], bfr[4];
#pragma unroll
        for (int i = 0; i < 4; i++)
            af[i] = *(const v8bf*)(sA + (wm + i * 16 + row16) * 32 + qswz);
#pragma unroll
        for (int j = 0; j < 4; j++)
            bfr[j] = *(const v8bf*)(sB + (wn + j * 16 + row16) * 32 + qswz);
#pragma unroll
        for (int i = 0; i < 4; i++)
#pragma unroll
            for (int j = 0; j < 4; j++)
                acc[i][j] = __builtin_amdgcn_mfma_f32_16x16x32_bf16(af[i], bfr[j], acc[i][j], 0, 0, 0);

        if (kt + 1 < NT) {
            if (kt + 2 < NT)
                asm volatile("s_waitcnt vmcnt(4)" ::: "memory");  // confirm kt+1
            else
                asm volatile("s_waitcnt vmcnt(0)" ::: "memory");  // tail drain
            __builtin_amdgcn_s_barrier();
        }
    }

#pragma unroll
    for (int i = 0; i < 4; i++) {
#pragma unroll
        for (int j = 0; j < 4; j++) {
            int col = bn * 128 + wn + j * 16 + row16;
            float bv = bias[col];
#pragma unroll
            for (int r = 0; r < 4; r++) {
                int row = bm * 128 + wm + i * 16 + quad * 4 + r;
                float v = acc[i][j][r] + bv;
                if (EPI == 1) v = 0.5f * v * (1.0f + erff(v * 0.70710678118f));
                if (EPI == 2) {
                    v += resid[(size_t)row * Nf + col];
                    ((float*)outv)[(size_t)row * Nf + col] = v;
                } else {
                    ((ushort_t*)outv)[(size_t)row * Nf + col] = f2b(v);
                }
            }
        }
    }
}

// ---------------- fused channel attention: out = softmax(q^T k / 32) @ v -----
// One block per (b_local, g), 256 threads / 4 waves.
// Phase 1 (QK^T): 16 n-chunks of 64, register-prefetched one chunk ahead so
//   global latency hides under the transpose-writes + MFMA of the previous
//   chunk. Scalar-transpose staging into sQt/sKt [96][72] (verified R6),
//   MFMA 2x2 waves of 48x48 (acc[3][3], verified R6).
// Softmax: S in LDS fp32 [96][97]; P written to LDS bf16 [96][104] (no
//   global round-trip; math identical to R6).
// Phase 2 (PV): P-fragments hoisted to registers once (18 v8bf per wave);
//   V chunks (64 rows) reg-prefetched -> ds_write_b128 into sV [64][104]
//   (2-way banked); per chunk per wave: 3 ds_read + 18 MFMA; epilogue
//   stores same layout as verified R6 attn_av.
__global__ __launch_bounds__(256) void attn_fused(
    const ushort_t* __restrict__ qkv, ushort_t* __restrict__ out)
{
    __shared__ __align__(16) char smem[57216];
    ushort_t* sQt = (ushort_t*)smem;                 // [96][72] bf16 (ph1)
    ushort_t* sKt = (ushort_t*)(smem + 13824);       // [96][72] bf16 (ph1)
    float*    sS  = (float*)smem;                    // [96][97] fp32 (softmax)
    ushort_t* sP  = (ushort_t*)(smem + 37248);       // [96][104] bf16 (ph2)
    ushort_t* sV  = (ushort_t*)smem;                 // [64][104] bf16 (ph2)

    int bg = blockIdx.x;
    int b = bg >> 3, g = bg & 7;
    int t = threadIdx.x;
    int wave = t >> 6, lane = t & 63;
    int wc = (wave >> 1) * 48, wd = (wave & 1) * 48;
    int row16 = lane & 15, quad = lane >> 4;

    // ---------- phase 1: S = q^T k over n ----------
    int li0 = t * 3;
    int r_[3], sg_[3];
#pragma unroll
    for (int i = 0; i < 3; i++) { r_[i] = (li0 + i) / 12; sg_[i] = (li0 + i) % 12; }

    v4f acc[3][3];
#pragma unroll
    for (int i = 0; i < 3; i++)
#pragma unroll
        for (int j = 0; j < 3; j++) acc[i][j] = (v4f){0.f, 0.f, 0.f, 0.f};

    uint4 uq[3], uk[3];
#pragma unroll
    for (int i = 0; i < 3; i++) {
        const ushort_t* p = qkv + ((size_t)(b * N_ + r_[i]) * 3) * C_ + g * HD_ + sg_[i] * 8;
        uq[i] = *(const uint4*)p;
        uk[i] = *(const uint4*)(p + C_);
    }

    for (int n0 = 0; n0 < N_; n0 += 64) {
        uint4 nq[3] = {}, nk[3] = {};
        bool more = (n0 + 64 < N_);
        if (more) {
#pragma unroll
            for (int i = 0; i < 3; i++) {
                const ushort_t* p = qkv + ((size_t)(b * N_ + n0 + 64 + r_[i]) * 3) * C_ + g * HD_ + sg_[i] * 8;
                nq[i] = *(const uint4*)p;
                nk[i] = *(const uint4*)(p + C_);
            }
        }
        __syncthreads();                 // prev chunk's MFMA reads done
#pragma unroll
        for (int i = 0; i < 3; i++) {
            union { uint4 v; ushort_t s[8]; } a, bu;
            a.v = uq[i]; bu.v = uk[i];
#pragma unroll
            for (int k2 = 0; k2 < 8; k2++) {
                sQt[(sg_[i] * 8 + k2) * 72 + r_[i]] = a.s[k2];
                sKt[(sg_[i] * 8 + k2) * 72 + r_[i]] = bu.s[k2];
            }
        }
        __syncthreads();                 // transpose visible
#pragma unroll
        for (int kk = 0; kk < 64; kk += 32) {
            v8bf af[3], bf2[3];
#pragma unroll
            for (int i = 0; i < 3; i++)
                af[i] = *(const v8bf*)(sQt + (wc + i * 16 + row16) * 72 + kk + quad * 8);
#pragma unroll
            for (int j = 0; j < 3; j++)
                bf2[j] = *(const v8bf*)(sKt + (wd + j * 16 + row16) * 72 + kk + quad * 8);
#pragma unroll
            for (int i = 0; i < 3; i++)
#pragma unroll
                for (int j = 0; j < 3; j++)
                    acc[i][j] = __builtin_amdgcn_mfma_f32_16x16x32_bf16(af[i], bf2[j], acc[i][j], 0, 0, 0);
        }
        if (more) {
#pragma unroll
            for (int i = 0; i < 3; i++) { uq[i] = nq[i]; uk[i] = nk[i]; }
        }
    }

    // ---------- softmax: S -> P (bf16, in LDS) ----------
    __syncthreads();                     // MFMA reads done; LDS reused as sS
#pragma unroll
    for (int i = 0; i < 3; i++)
#pragma unroll
        for (int j = 0; j < 3; j++)
#pragma unroll
            for (int r = 0; r < 4; r++) {
                int c = wc + i * 16 + quad * 4 + r;
                int d = wd + j * 16 + row16;
                sS[c * 97 + d] = acc[i][j][r] * 0.03125f;
            }
    __syncthreads();
    if (t < 96) {
        float mx = -1e30f;
#pragma unroll 8
        for (int d = 0; d < 96; d++) mx = fmaxf(mx, sS[t * 97 + d]);
        float sum = 0.f;
#pragma unroll 8
        for (int d = 0; d < 96; d++) sum += __expf(sS[t * 97 + d] - mx);
        float rs = 1.0f / sum;
#pragma unroll 8
        for (int d = 0; d < 96; d++)
            sP[t * 104 + d] = f2b(__expf(sS[t * 97 + d] - mx) * rs);
    }
    __syncthreads();

    // ---------- phase 2: out = P @ v ----------
    // hoist P fragments (wave's 96 cols x K=96): pf[kk][j]
    v8bf pf[3][6];
#pragma unroll
    for (int kk = 0; kk < 3; kk++)
#pragma unroll
        for (int j = 0; j < 6; j++)
            pf[kk][j] = *(const v8bf*)(sP + (j * 16 + row16) * 104 + kk * 32 + quad * 8);

    int li = t;                          // V staging: 3 segs/thread
    int vr_[3], vsg_[3];
#pragma unroll
    for (int i = 0; i < 3; i++) { vr_[i] = (li + i * 256) / 12; vsg_[i] = (li + i * 256) % 12; }

    uint4 uv[3];
#pragma unroll
    for (int i = 0; i < 3; i++)
        uv[i] = *(const uint4*)(qkv + ((size_t)(b * N_ + vr_[i]) * 3 + 2) * C_ + g * HD_ + vsg_[i] * 8);

    for (int n0 = 0; n0 < N_; n0 += 64) {
        uint4 nv[3] = {};
        bool more = (n0 + 64 < N_);
        if (more) {
#pragma unroll
            for (int i = 0; i < 3; i++)
                nv[i] = *(const uint4*)(qkv + ((size_t)(b * N_ + n0 + 64 + vr_[i]) * 3 + 2) * C_ + g * HD_ + vsg_[i] * 8);
        }
        __syncthreads();                 // prev chunk's V reads done (iter0: pf reads done)
#pragma unroll
        for (int i = 0; i < 3; i++)
            *(uint4*)(sV + vr_[i] * 104 + vsg_[i] * 8) = uv[i];
        __syncthreads();                 // V visible
        v4f a2[6];
#pragma unroll
        for (int j = 0; j < 6; j++) a2[j] = (v4f){0.f, 0.f, 0.f, 0.f};
#pragma unroll
        for (int kk = 0; kk < 3; kk++) {
            v8bf av = *(const v8bf*)(sV + (wave * 16 + row16) * 104 + kk * 32 + quad * 8);
#pragma unroll
            for (int j = 0; j < 6; j++)
                a2[j] = __builtin_amdgcn_mfma_f32_16x16x32_bf16(av, pf[kk][j], a2[j], 0, 0, 0);
        }
#pragma unroll
        for (int j = 0; j < 6; j++)
#pragma unroll
            for (int rr = 0; rr < 4; rr++) {
                int n = n0 + wave * 16 + quad * 4 + rr;
                out[(size_t)(b * N_ + n) * C_ + g * HD_ + j * 16 + row16] = f2b(a2[j][rr]);
            }
        if (more) {
#pragma unroll
            for (int i = 0; i < 3; i++) uv[i] = nv[i];
        }
    }
}

// -----------------------------------------------------------------------------
// bf16-internal chunked pipeline. Residual chain (x1/x2/x3/out) fp32.
extern "C" void kernel_launch(void* const* d_in, const int* in_sizes, int n_in,
                              void* d_out, int out_size, void* d_ws, size_t ws_size,
                              hipStream_t stream)
{
    const float* x      = (const float*)d_in[0];
    const float* dw1_w  = (const float*)d_in[3];
    const float* dw1_b  = (const float*)d_in[4];
    const float* ln1_g  = (const float*)d_in[5];
    const float* ln1_b  = (const float*)d_in[6];
    const float* qkv_w  = (const float*)d_in[7];
    const float* qkv_b  = (const float*)d_in[8];
    const float* proj_w = (const float*)d_in[9];
    const float* proj_b = (const float*)d_in[10];
    const float* dw2_w  = (const float*)d_in[11];
    const float* dw2_b  = (const float*)d_in[12];
    const float* ln2_g  = (const float*)d_in[13];
    const float* ln2_b  = (const float*)d_in[14];
    const float* fc1_w  = (const float*)d_in[15];
    const float* fc1_b  = (const float*)d_in[16];
    const float* fc2_w  = (const float*)d_in[17];
    const float* fc2_b  = (const float*)d_in[18];
    float* outp = (float*)d_out;    // holds x1, then x3, then final out

    char* ws = (char*)d_ws;
    // bf16 weight arena
    ushort_t* qkvW = (ushort_t*)ws;                          // 2304*768
    ushort_t* projW = qkvW + 2304 * 768;                     // 768*768
    ushort_t* fc1W = projW + 768 * 768;                      // 3072*768
    ushort_t* fc2W = fc1W + 3072 * 768;                      // 768*3072
    const size_t WB = (size_t)(2304*768 + 768*768 + 3072*768 + 768*3072) * 2; // 14,155,776
    // transposed dwconv weights [9][768] fp32
    float* wt1 = (float*)(ws + WB);
    float* wt2 = wt1 + 9 * C_;
    const size_t WTB = 2 * 9 * C_ * sizeof(float);           // 55,296

    size_t CB = 32;
    while (CB > 1 && WB + WTB + CB * 12730368ull > ws_size) CB >>= 1;
    const size_t R = CB * 1024;
    char* act = ws + WB + WTB;
    ushort_t* L  = (ushort_t*)act;                           // [R,768] bf16
    ushort_t* Ab = (ushort_t*)(act + R * C_ * 2);            // [R,768] bf16
    float*    X2 = (float*)(act + 2 * R * C_ * 2);           // [R,768] fp32
    ushort_t* D  = (ushort_t*)(act + 2 * R * C_ * 2 + R * C_ * 4 + CB * 147456);

    // 0. weight conversion fp32 -> bf16 (1 launch) ; dwconv transpose (1)
    cvt_all<<<6912, 256, 0, stream>>>(qkv_w, proj_w, fc1_w, fc2_w, qkvW);
    transpose_w2<<<54, 256, 0, stream>>>(dw1_w, dw2_w, wt1, wt2);

    // 1. x1 = x + dwconv1(x) -> d_out  (full, fp32)
    dwconv_add<<<32 * 32 * 6, 256, 0, stream>>>(x, wt1, dw1_b, outp);

    const int nchunk = (int)(32 / CB);
    for (int c = 0; c < nchunk; c++) {
        float* xc = outp + (size_t)c * R * C_;   // x1 chunk, later x3 chunk
        // ln1 -> L (bf16)
        layernorm_bf<<<(int)R, 256, 0, stream>>>(xc, ln1_g, ln1_b, L);
        // qkv = L @ qkvW^T + b -> D (bf16)
        gemm_bt<0><<<dim3((int)R / 128, 2304 / 128), 256, 0, stream>>>(
            L, qkvW, qkv_b, nullptr, D, (int)R, 2304, C_);
        // A = softmax(q^T k / 32) @ v  (fused, MFMA, P stays in LDS)
        attn_fused<<<(int)CB * 8, 256, 0, stream>>>(D, Ab);
        // x2 = x1 + A @ projW^T + b -> X2 (fp32)
        gemm_bt<2><<<dim3((int)R / 128, C_ / 128), 256, 0, stream>>>(
            Ab, projW, proj_b, xc, X2, (int)R, C_, C_);
        // x3 = x2 + dwconv2(x2) -> d_out chunk (fp32)
        dwconv_add<<<(int)(R / 1024) * 32 * 6, 256, 0, stream>>>(X2, wt2, dw2_b, xc);
        // ln2 -> L (bf16)
        layernorm_bf<<<(int)R, 256, 0, stream>>>(xc, ln2_g, ln2_b, L);
        // h = gelu(L @ fc1W^T + b) -> D (bf16)
        gemm_bt<1><<<dim3((int)R / 128, CH_ / 128), 256, 0, stream>>>(
            L, fc1W, fc1_b, nullptr, D, (int)R, CH_, C_);
        // out = x3 + h @ fc2W^T + b -> d_out chunk (fp32, alias-safe)
        gemm_bt<2><<<dim3((int)R / 128, C_ / 128), 256, 0, stream>>>(
            D, fc2W, fc2_b, xc, xc, (int)R, C_, CH_);
    }
}

// Round 8
// 1152.889 us; speedup vs baseline: 1.0586x; 1.0586x over previous
//
#include <hip/hip_runtime.h>

typedef unsigned short ushort_t;
typedef __bf16 v8bf __attribute__((ext_vector_type(8)));
typedef float v4f __attribute__((ext_vector_type(4)));

#define B_ 32
#define N_ 1024
#define C_ 768
#define G_ 8
#define HD_ 96
#define CH_ 3072
#define M_ 32768  // B*N

static __device__ __forceinline__ float b2f(ushort_t u) {
    union { float f; unsigned int i; } z; z.i = ((unsigned int)u) << 16; return z.f;
}
static __device__ __forceinline__ ushort_t f2b(float f) {
    unsigned int u = __float_as_uint(f);
    u += 0x7fff + ((u >> 16) & 1);   // RNE
    return (ushort_t)(u >> 16);
}
static __device__ __forceinline__ unsigned int pk2(float a, float b) {
    return (unsigned int)f2b(a) | ((unsigned int)f2b(b) << 16);
}

#define GLOAD_LDS16(g, l) __builtin_amdgcn_global_load_lds( \
    (const __attribute__((address_space(1))) unsigned int*)(g), \
    (__attribute__((address_space(3))) unsigned int*)(l), 16, 0, 0)

// ---------------- fp32 -> bf16 weight conversion, all 4 weights in 1 launch ---
__global__ __launch_bounds__(256) void cvt_all(
    const float* __restrict__ a, const float* __restrict__ b,
    const float* __restrict__ c, const float* __restrict__ d,
    ushort_t* __restrict__ o)
{
    int blk = blockIdx.x;            // 6912 total
    const float* src; ushort_t* dst; int off;
    if (blk < 1728)      { src = a; dst = o;                          off = blk; }
    else if (blk < 2304) { src = b; dst = o + 2304 * 768;             off = blk - 1728; }
    else if (blk < 4608) { src = c; dst = o + 2304 * 768 + 768 * 768; off = blk - 2304; }
    else                 { src = d; dst = o + 2304 * 768 + 768 * 768 + 3072 * 768; off = blk - 4608; }
    int i = (off * 256 + threadIdx.x) * 4;
    float4 v = *(const float4*)(src + i);
    uint2 p; p.x = pk2(v.x, v.y); p.y = pk2(v.z, v.w);
    *(uint2*)(dst + i) = p;
}

// ---------------- dwconv weight transpose: [C,3,3] -> [9][C] fp32, both -------
__global__ __launch_bounds__(256) void transpose_w2(
    const float* __restrict__ w1, const float* __restrict__ w2,
    float* __restrict__ wt1, float* __restrict__ wt2)
{
    int blk = blockIdx.x;            // 54
    const float* w = (blk < 27) ? w1 : w2;
    float* wt = (blk < 27) ? wt1 : wt2;
    int i = (blk % 27) * 256 + threadIdx.x;
    int c = i / 9, k = i % 9;
    wt[k * C_ + c] = w[i];
}

// ---------------- depthwise 3x3 conv + residual (fp32): out = x + conv(x) ----
// 2-row register tiling: each thread computes 2 h-rows x 4 w x 4 ch from
// tap[4][6] (rows h0-1..h0+2 shared in-register between the two output rows).
// Block covers (b, h-pair) x 32 w x 128 ch. grid = 32*16*6 = 3072.
__global__ __launch_bounds__(256) void dwconv_add(
    const float* __restrict__ xin, const float* __restrict__ wt,
    const float* __restrict__ bias, float* __restrict__ out)
{
    int t = threadIdx.x;
    int bid = blockIdx.x;
    int cblk = bid % 6;                  // 6 = 768/128
    int bhp = bid / 6;                   // b*16 + hp
    int b = bhp >> 4, hp = bhp & 15;
    int h0 = hp * 2;
    int tw = t >> 5;                     // 0..7 -> 4-pixel group
    int c0 = cblk * 128 + (t & 31) * 4;  // channel base (float4)
    int w0 = tw * 4;

    float4 tap[4][6];
#pragma unroll
    for (int dh = 0; dh < 4; dh++) {
        int hh = h0 + dh - 1;
        bool hok = (hh >= 0) && (hh < 32);   // block-uniform branch
#pragma unroll
        for (int dw = 0; dw < 6; dw++) {
            int ww = w0 + dw - 1;
            bool ok = hok && (ww >= 0) && (ww < 32);
            if (ok)
                tap[dh][dw] = *(const float4*)(
                    xin + (size_t)((b << 10) | (hh << 5) | ww) * C_ + c0);
            else
                tap[dh][dw] = make_float4(0.f, 0.f, 0.f, 0.f);
        }
    }
    float4 wv[9];
#pragma unroll
    for (int k = 0; k < 9; k++)
        wv[k] = *(const float4*)(wt + k * C_ + c0);
    float4 bv = *(const float4*)(bias + c0);

#pragma unroll
    for (int row = 0; row < 2; row++) {
#pragma unroll
        for (int i = 0; i < 4; i++) {
            float4 acc = bv;
#pragma unroll
            for (int dh = 0; dh < 3; dh++)
#pragma unroll
                for (int dw = 0; dw < 3; dw++) {
                    float4 xv = tap[row + dh][i + dw];
                    float4 wk = wv[dh * 3 + dw];
                    acc.x += wk.x * xv.x; acc.y += wk.y * xv.y;
                    acc.z += wk.z * xv.z; acc.w += wk.w * xv.w;
                }
            float4 xr = tap[row + 1][i + 1];   // residual, always in-bounds
            acc.x += xr.x; acc.y += xr.y; acc.z += xr.z; acc.w += xr.w;
            *(float4*)(out + (size_t)((b << 10) | ((h0 + row) << 5) | (w0 + i)) * C_ + c0) = acc;
        }
    }
}

// ---------------- layernorm over C=768: fp32 in -> bf16 out -------------------
__global__ __launch_bounds__(256) void layernorm_bf(
    const float* __restrict__ xin, const float* __restrict__ g,
    const float* __restrict__ bb, ushort_t* __restrict__ out)
{
    int row = blockIdx.x;
    int t = threadIdx.x;
    const float* xr = xin + (size_t)row * C_;
    float x0 = xr[t], x1 = xr[t + 256], x2 = xr[t + 512];
    float s1 = x0 + x1 + x2;
    float s2 = x0 * x0 + x1 * x1 + x2 * x2;
#pragma unroll
    for (int o = 32; o > 0; o >>= 1) {
        s1 += __shfl_xor(s1, o);
        s2 += __shfl_xor(s2, o);
    }
    __shared__ float red[8];
    if ((t & 63) == 0) { red[(t >> 6) * 2] = s1; red[(t >> 6) * 2 + 1] = s2; }
    __syncthreads();
    s1 = red[0] + red[2] + red[4] + red[6];
    s2 = red[1] + red[3] + red[5] + red[7];
    float m = s1 * (1.0f / 768.0f);
    float var = s2 * (1.0f / 768.0f) - m * m;
    float inv = rsqrtf(var + 1e-5f);
    ushort_t* orow = out + (size_t)row * C_;
    orow[t]       = f2b((x0 - m) * inv * g[t]       + bb[t]);
    orow[t + 256] = f2b((x1 - m) * inv * g[t + 256] + bb[t + 256]);
    orow[t + 512] = f2b((x2 - m) * inv * g[t + 512] + bb[t + 512]);
}

// ---------------- bf16 GEMM: 128x128, ring-3, counted vmcnt, T2 swizzle -------
// (R4 known-good: fc2 146us, conflicts 0)
template <int EPI>
__global__ __launch_bounds__(256) void gemm_bt(
    const ushort_t* __restrict__ A, const ushort_t* __restrict__ W,
    const float* __restrict__ bias, const float* __restrict__ resid,
    void* __restrict__ outv, int M, int Nf, int K)
{
    __shared__ __align__(16) ushort_t ring[3][2][128 * 32];  // 48 KB
    int t = threadIdx.x;
    int bm = blockIdx.x;   // M/128
    int bn = blockIdx.y;   // Nf/128
    int wave = t >> 6, lane = t & 63;
    int wm = (wave >> 1) * 64;
    int wn = (wave & 1) * 64;
    int row16 = lane & 15;
    int quad = lane >> 4;
    int qswz = (quad * 8) ^ (((row16 >> 1) & 3) * 8);  // read-side swizzle

    int r0 = wave * 16 + (lane >> 2);
    int r1 = (wave + 4) * 16 + (lane >> 2);
    int c8s = ((lane & 3) ^ ((lane >> 3) & 3)) * 8;
    const ushort_t* Ag0 = A + (size_t)(bm * 128 + r0) * K + c8s;
    const ushort_t* Ag1 = A + (size_t)(bm * 128 + r1) * K + c8s;
    const ushort_t* Wg0 = W + (size_t)(bn * 128 + r0) * K + c8s;
    const ushort_t* Wg1 = W + (size_t)(bn * 128 + r1) * K + c8s;

    v4f acc[4][4];
#pragma unroll
    for (int i = 0; i < 4; i++)
#pragma unroll
        for (int j = 0; j < 4; j++) acc[i][j] = (v4f){0.f, 0.f, 0.f, 0.f};

    const int NT = K >> 5;   // K-tiles of 32

    auto STAGE = [&](int kt) {
        int s = kt % 3;
        ushort_t* a = &ring[s][0][0];
        ushort_t* b = &ring[s][1][0];
        int off = kt * 32;
        GLOAD_LDS16(Ag0 + off, a + wave * 512);
        GLOAD_LDS16(Ag1 + off, a + (wave + 4) * 512);
        GLOAD_LDS16(Wg0 + off, b + wave * 512);
        GLOAD_LDS16(Wg1 + off, b + (wave + 4) * 512);
    };

    STAGE(0);
    STAGE(1);
    asm volatile("s_waitcnt vmcnt(4)" ::: "memory");
    __builtin_amdgcn_s_barrier();

    for (int kt = 0; kt < NT; ++kt) {
        if (kt + 2 < NT) STAGE(kt + 2);          // into slot freed at kt-1

        const ushort_t* sA = &ring[kt % 3][0][0];
        const ushort_t* sB = &ring[kt % 3][1][0];
        v8bf af[4], bfr[4];
#pragma unroll
        for (int i = 0; i < 4; i++)
            af[i] = *(const v8bf*)(sA + (wm + i * 16 + row16) * 32 + qswz);
#pragma unroll
        for (int j = 0; j < 4; j++)
            bfr[j] = *(const v8bf*)(sB + (wn + j * 16 + row16) * 32 + qswz);
#pragma unroll
        for (int i = 0; i < 4; i++)
#pragma unroll
            for (int j = 0; j < 4; j++)
                acc[i][j] = __builtin_amdgcn_mfma_f32_16x16x32_bf16(af[i], bfr[j], acc[i][j], 0, 0, 0);

        if (kt + 1 < NT) {
            if (kt + 2 < NT)
                asm volatile("s_waitcnt vmcnt(4)" ::: "memory");  // confirm kt+1
            else
                asm volatile("s_waitcnt vmcnt(0)" ::: "memory");  // tail drain
            __builtin_amdgcn_s_barrier();
        }
    }

#pragma unroll
    for (int i = 0; i < 4; i++) {
#pragma unroll
        for (int j = 0; j < 4; j++) {
            int col = bn * 128 + wn + j * 16 + row16;
            float bv = bias[col];
#pragma unroll
            for (int r = 0; r < 4; r++) {
                int row = bm * 128 + wm + i * 16 + quad * 4 + r;
                float v = acc[i][j][r] + bv;
                if (EPI == 1) v = 0.5f * v * (1.0f + erff(v * 0.70710678118f));
                if (EPI == 2) {
                    v += resid[(size_t)row * Nf + col];
                    ((float*)outv)[(size_t)row * Nf + col] = v;
                } else {
                    ((ushort_t*)outv)[(size_t)row * Nf + col] = f2b(v);
                }
            }
        }
    }
}

// ---------------- channel attention (MFMA + reg-prefetch): P = softmax(qk/32) -
// One block per (b_local, g). Phase-1 staging register-prefetches the next
// n-chunk's 6 uint4 loads so HBM latency hides under transpose+MFMA of the
// current chunk (code verified in R7's fused kernel). P written to global.
__global__ __launch_bounds__(256) void chan_attn(
    const ushort_t* __restrict__ qkv, ushort_t* __restrict__ P)
{
    __shared__ __align__(16) char smem[96 * 97 * 4];   // 37,248 B
    ushort_t* sQt = (ushort_t*)smem;                   // [96][72] bf16
    ushort_t* sKt = (ushort_t*)(smem + 13824);         // [96][72] bf16
    float* sS = (float*)smem;                          // [96][97] fp32 (after)
    int bg = blockIdx.x;
    int b = bg >> 3, g = bg & 7;
    int t = threadIdx.x;
    int wave = t >> 6, lane = t & 63;
    int wc = (wave >> 1) * 48, wd = (wave & 1) * 48;
    int row16 = lane & 15, quad = lane >> 4;

    int li0 = t * 3;
    int r_[3], sg_[3];
#pragma unroll
    for (int i = 0; i < 3; i++) { r_[i] = (li0 + i) / 12; sg_[i] = (li0 + i) % 12; }

    v4f acc[3][3];
#pragma unroll
    for (int i = 0; i < 3; i++)
#pragma unroll
        for (int j = 0; j < 3; j++) acc[i][j] = (v4f){0.f, 0.f, 0.f, 0.f};

    uint4 uq[3], uk[3];
#pragma unroll
    for (int i = 0; i < 3; i++) {
        const ushort_t* p = qkv + ((size_t)(b * N_ + r_[i]) * 3) * C_ + g * HD_ + sg_[i] * 8;
        uq[i] = *(const uint4*)p;
        uk[i] = *(const uint4*)(p + C_);
    }

    for (int n0 = 0; n0 < N_; n0 += 64) {
        uint4 nq[3] = {}, nk[3] = {};
        bool more = (n0 + 64 < N_);
        if (more) {
#pragma unroll
            for (int i = 0; i < 3; i++) {
                const ushort_t* p = qkv + ((size_t)(b * N_ + n0 + 64 + r_[i]) * 3) * C_ + g * HD_ + sg_[i] * 8;
                nq[i] = *(const uint4*)p;
                nk[i] = *(const uint4*)(p + C_);
            }
        }
        __syncthreads();                 // prev chunk's MFMA reads done
#pragma unroll
        for (int i = 0; i < 3; i++) {
            union { uint4 v; ushort_t s[8]; } a, bu;
            a.v = uq[i]; bu.v = uk[i];
#pragma unroll
            for (int k2 = 0; k2 < 8; k2++) {
                sQt[(sg_[i] * 8 + k2) * 72 + r_[i]] = a.s[k2];
                sKt[(sg_[i] * 8 + k2) * 72 + r_[i]] = bu.s[k2];
            }
        }
        __syncthreads();                 // transpose visible
#pragma unroll
        for (int kk = 0; kk < 64; kk += 32) {
            v8bf af[3], bf2[3];
#pragma unroll
            for (int i = 0; i < 3; i++)
                af[i] = *(const v8bf*)(sQt + (wc + i * 16 + row16) * 72 + kk + quad * 8);
#pragma unroll
            for (int j = 0; j < 3; j++)
                bf2[j] = *(const v8bf*)(sKt + (wd + j * 16 + row16) * 72 + kk + quad * 8);
#pragma unroll
            for (int i = 0; i < 3; i++)
#pragma unroll
                for (int j = 0; j < 3; j++)
                    acc[i][j] = __builtin_amdgcn_mfma_f32_16x16x32_bf16(af[i], bf2[j], acc[i][j], 0, 0, 0);
        }
        if (more) {
#pragma unroll
            for (int i = 0; i < 3; i++) { uq[i] = nq[i]; uk[i] = nk[i]; }
        }
    }
    __syncthreads();                     // last MFMA reads done; reuse LDS as sS
#pragma unroll
    for (int i = 0; i < 3; i++)
#pragma unroll
        for (int j = 0; j < 3; j++)
#pragma unroll
            for (int r = 0; r < 4; r++) {
                int c = wc + i * 16 + quad * 4 + r;    // MFMA C: row = quad*4+reg
                int d = wd + j * 16 + row16;           // col = lane&15
                sS[c * 97 + d] = acc[i][j][r] * 0.03125f;
            }
    __syncthreads();
    if (t < 96) {
        float mx = -1e30f;
        for (int d = 0; d < 96; d++) mx = fmaxf(mx, sS[t * 97 + d]);
        float sum = 0.f;
        for (int d = 0; d < 96; d++) sum += __expf(sS[t * 97 + d] - mx);
        float rs = 1.0f / sum;
        ushort_t* prow = P + (size_t)bg * 9216 + t * 96;
        for (int d = 0; d < 96; d++) prow[d] = f2b(__expf(sS[t * 97 + d] - mx) * rs);
    }
}

// ---------------- attention apply (MFMA): out[n,c] = sum_d P[c,d] V[n,d] -----
// (R6 known-good) Per (b_local, g, nchunk of 256 rows): A = V[256n][96d],
// B = P[96c][96d]. Rows padded to 104. 4 waves x 64 rows, acc[4][6].
__global__ __launch_bounds__(256) void attn_av(
    const ushort_t* __restrict__ qkv, const ushort_t* __restrict__ P,
    ushort_t* __restrict__ out)
{
    __shared__ __align__(16) ushort_t sV[256 * 104];  // 53,248 B
    __shared__ __align__(16) ushort_t sP[96 * 104];   // 19,968 B
    int blk = blockIdx.x;                 // b_local*32 + g*4 + nch
    int nch = blk & 3, g = (blk >> 2) & 7, b = blk >> 5;
    int t = threadIdx.x;
    int n0 = nch * 256;
#pragma unroll
    for (int i = 0; i < 12; i++) {
        int li = t + i * 256;             // 0..3071
        int r = li / 12, sg = li % 12;
        size_t voff = ((size_t)(b * N_ + n0 + r) * 3 + 2) * C_ + g * HD_ + sg * 8;
        *(uint4*)(sV + r * 104 + sg * 8) = *(const uint4*)(qkv + voff);
    }
#pragma unroll
    for (int i = 0; i < 5; i++) {
        int li = t + i * 256;
        if (li < 1152) {
            int r = li / 12, sg = li % 12;
            *(uint4*)(sP + r * 104 + sg * 8) =
                *(const uint4*)(P + (size_t)(b * 8 + g) * 9216 + li * 8);
        }
    }
    __syncthreads();
    int wave = t >> 6, lane = t & 63;
    int wm = wave * 64;
    int row16 = lane & 15, quad = lane >> 4;
    v4f acc[4][6];
#pragma unroll
    for (int i = 0; i < 4; i++)
#pragma unroll
        for (int j = 0; j < 6; j++) acc[i][j] = (v4f){0.f, 0.f, 0.f, 0.f};
#pragma unroll
    for (int kk = 0; kk < 96; kk += 32) {
        v8bf af[4], bfr[6];
#pragma unroll
        for (int i = 0; i < 4; i++)
            af[i] = *(const v8bf*)(sV + (wm + i * 16 + row16) * 104 + kk + quad * 8);
#pragma unroll
        for (int j = 0; j < 6; j++)
            bfr[j] = *(const v8bf*)(sP + (j * 16 + row16) * 104 + kk + quad * 8);
#pragma unroll
        for (int i = 0; i < 4; i++)
#pragma unroll
            for (int j = 0; j < 6; j++)
                acc[i][j] = __builtin_amdgcn_mfma_f32_16x16x32_bf16(af[i], bfr[j], acc[i][j], 0, 0, 0);
    }
#pragma unroll
    for (int i = 0; i < 4; i++)
#pragma unroll
        for (int j = 0; j < 6; j++)
#pragma unroll
            for (int r = 0; r < 4; r++) {
                int n = n0 + wm + i * 16 + quad * 4 + r;
                int c = j * 16 + row16;
                out[(size_t)(b * N_ + n) * C_ + g * HD_ + c] = f2b(acc[i][j][r]);
            }
}

// -----------------------------------------------------------------------------
// bf16-internal chunked pipeline. Residual chain (x1/x2/x3/out) fp32.
extern "C" void kernel_launch(void* const* d_in, const int* in_sizes, int n_in,
                              void* d_out, int out_size, void* d_ws, size_t ws_size,
                              hipStream_t stream)
{
    const float* x      = (const float*)d_in[0];
    const float* dw1_w  = (const float*)d_in[3];
    const float* dw1_b  = (const float*)d_in[4];
    const float* ln1_g  = (const float*)d_in[5];
    const float* ln1_b  = (const float*)d_in[6];
    const float* qkv_w  = (const float*)d_in[7];
    const float* qkv_b  = (const float*)d_in[8];
    const float* proj_w = (const float*)d_in[9];
    const float* proj_b = (const float*)d_in[10];
    const float* dw2_w  = (const float*)d_in[11];
    const float* dw2_b  = (const float*)d_in[12];
    const float* ln2_g  = (const float*)d_in[13];
    const float* ln2_b  = (const float*)d_in[14];
    const float* fc1_w  = (const float*)d_in[15];
    const float* fc1_b  = (const float*)d_in[16];
    const float* fc2_w  = (const float*)d_in[17];
    const float* fc2_b  = (const float*)d_in[18];
    float* outp = (float*)d_out;    // holds x1, then x3, then final out

    char* ws = (char*)d_ws;
    // bf16 weight arena
    ushort_t* qkvW = (ushort_t*)ws;                          // 2304*768
    ushort_t* projW = qkvW + 2304 * 768;                     // 768*768
    ushort_t* fc1W = projW + 768 * 768;                      // 3072*768
    ushort_t* fc2W = fc1W + 3072 * 768;                      // 768*3072
    const size_t WB = (size_t)(2304*768 + 768*768 + 3072*768 + 768*3072) * 2; // 14,155,776
    // transposed dwconv weights [9][768] fp32
    float* wt1 = (float*)(ws + WB);
    float* wt2 = wt1 + 9 * C_;
    const size_t WTB = 2 * 9 * C_ * sizeof(float);           // 55,296

    size_t CB = 32;
    while (CB > 1 && WB + WTB + CB * 12730368ull > ws_size) CB >>= 1;
    const size_t R = CB * 1024;
    char* act = ws + WB + WTB;
    ushort_t* L  = (ushort_t*)act;                           // [R,768] bf16
    ushort_t* Ab = (ushort_t*)(act + R * C_ * 2);            // [R,768] bf16
    float*    X2 = (float*)(act + 2 * R * C_ * 2);           // [R,768] fp32
    ushort_t* P  = (ushort_t*)(act + 2 * R * C_ * 2 + R * C_ * 4);
    ushort_t* D  = (ushort_t*)(act + 2 * R * C_ * 2 + R * C_ * 4 + CB * 147456);

    // 0. weight conversion fp32 -> bf16 (1 launch) ; dwconv transpose (1)
    cvt_all<<<6912, 256, 0, stream>>>(qkv_w, proj_w, fc1_w, fc2_w, qkvW);
    transpose_w2<<<54, 256, 0, stream>>>(dw1_w, dw2_w, wt1, wt2);

    // 1. x1 = x + dwconv1(x) -> d_out  (full, fp32)
    dwconv_add<<<32 * 16 * 6, 256, 0, stream>>>(x, wt1, dw1_b, outp);

    const int nchunk = (int)(32 / CB);
    for (int c = 0; c < nchunk; c++) {
        float* xc = outp + (size_t)c * R * C_;   // x1 chunk, later x3 chunk
        // ln1 -> L (bf16)
        layernorm_bf<<<(int)R, 256, 0, stream>>>(xc, ln1_g, ln1_b, L);
        // qkv = L @ qkvW^T + b -> D (bf16)
        gemm_bt<0><<<dim3((int)R / 128, 2304 / 128), 256, 0, stream>>>(
            L, qkvW, qkv_b, nullptr, D, (int)R, 2304, C_);
        // P = softmax(q^T k / 32)  (MFMA, reg-prefetch)
        chan_attn<<<(int)CB * 8, 256, 0, stream>>>(D, P);
        // A = P @ v (MFMA)
        attn_av<<<(int)CB * 32, 256, 0, stream>>>(D, P, Ab);
        // x2 = x1 + A @ projW^T + b -> X2 (fp32)
        gemm_bt<2><<<dim3((int)R / 128, C_ / 128), 256, 0, stream>>>(
            Ab, projW, proj_b, xc, X2, (int)R, C_, C_);
        // x3 = x2 + dwconv2(x2) -> d_out chunk (fp32)
        dwconv_add<<<(int)(R / 1024) * 16 * 6, 256, 0, stream>>>(X2, wt2, dw2_b, xc);
        // ln2 -> L (bf16)
        layernorm_bf<<<(int)R, 256, 0, stream>>>(xc, ln2_g, ln2_b, L);
        // h = gelu(L @ fc1W^T + b) -> D (bf16)
        gemm_bt<1><<<dim3((int)R / 128, CH_ / 128), 256, 0, stream>>>(
            L, fc1W, fc1_b, nullptr, D, (int)R, CH_, C_);
        // out = x3 + h @ fc2W^T + b -> d_out chunk (fp32, alias-safe)
        gemm_bt<2><<<dim3((int)R / 128, C_ / 128), 256, 0, stream>>>(
            D, fc2W, fc2_b, xc, xc, (int)R, C_, CH_);
    }
}

// Round 9
// 1098.709 us; speedup vs baseline: 1.1108x; 1.0493x over previous
//
#include <hip/hip_runtime.h>

typedef unsigned short ushort_t;
typedef __bf16 v8bf __attribute__((ext_vector_type(8)));
typedef float v4f __attribute__((ext_vector_type(4)));

#define B_ 32
#define N_ 1024
#define C_ 768
#define G_ 8
#define HD_ 96
#define CH_ 3072
#define M_ 32768  // B*N

static __device__ __forceinline__ float b2f(ushort_t u) {
    union { float f; unsigned int i; } z; z.i = ((unsigned int)u) << 16; return z.f;
}
static __device__ __forceinline__ ushort_t f2b(float f) {
    unsigned int u = __float_as_uint(f);
    u += 0x7fff + ((u >> 16) & 1);   // RNE
    return (ushort_t)(u >> 16);
}
static __device__ __forceinline__ unsigned int pk2(float a, float b) {
    return (unsigned int)f2b(a) | ((unsigned int)f2b(b) << 16);
}

#define GLOAD_LDS16(g, l) __builtin_amdgcn_global_load_lds( \
    (const __attribute__((address_space(1))) unsigned int*)(g), \
    (__attribute__((address_space(3))) unsigned int*)(l), 16, 0, 0)

// ---------------- fp32 -> bf16 weight conversion, all 4 weights in 1 launch ---
__global__ __launch_bounds__(256) void cvt_all(
    const float* __restrict__ a, const float* __restrict__ b,
    const float* __restrict__ c, const float* __restrict__ d,
    ushort_t* __restrict__ o)
{
    int blk = blockIdx.x;            // 6912 total
    const float* src; ushort_t* dst; int off;
    if (blk < 1728)      { src = a; dst = o;                          off = blk; }
    else if (blk < 2304) { src = b; dst = o + 2304 * 768;             off = blk - 1728; }
    else if (blk < 4608) { src = c; dst = o + 2304 * 768 + 768 * 768; off = blk - 2304; }
    else                 { src = d; dst = o + 2304 * 768 + 768 * 768 + 3072 * 768; off = blk - 4608; }
    int i = (off * 256 + threadIdx.x) * 4;
    float4 v = *(const float4*)(src + i);
    uint2 p; p.x = pk2(v.x, v.y); p.y = pk2(v.z, v.w);
    *(uint2*)(dst + i) = p;
}

// ---------------- dwconv weight transpose: [C,3,3] -> [9][C] fp32, both -------
__global__ __launch_bounds__(256) void transpose_w2(
    const float* __restrict__ w1, const float* __restrict__ w2,
    float* __restrict__ wt1, float* __restrict__ wt2)
{
    int blk = blockIdx.x;            // 54
    const float* w = (blk < 27) ? w1 : w2;
    float* wt = (blk < 27) ? wt1 : wt2;
    int i = (blk % 27) * 256 + threadIdx.x;
    int c = i / 9, k = i % 9;
    wt[k * C_ + c] = w[i];
}

// ---------------- depthwise 3x3 conv + residual (fp32): out = x + conv(x) ----
// 2-row register tiling (R8 known-good).
__global__ __launch_bounds__(256) void dwconv_add(
    const float* __restrict__ xin, const float* __restrict__ wt,
    const float* __restrict__ bias, float* __restrict__ out)
{
    int t = threadIdx.x;
    int bid = blockIdx.x;
    int cblk = bid % 6;                  // 6 = 768/128
    int bhp = bid / 6;                   // b*16 + hp
    int b = bhp >> 4, hp = bhp & 15;
    int h0 = hp * 2;
    int tw = t >> 5;                     // 0..7 -> 4-pixel group
    int c0 = cblk * 128 + (t & 31) * 4;  // channel base (float4)
    int w0 = tw * 4;

    float4 tap[4][6];
#pragma unroll
    for (int dh = 0; dh < 4; dh++) {
        int hh = h0 + dh - 1;
        bool hok = (hh >= 0) && (hh < 32);   // block-uniform branch
#pragma unroll
        for (int dw = 0; dw < 6; dw++) {
            int ww = w0 + dw - 1;
            bool ok = hok && (ww >= 0) && (ww < 32);
            if (ok)
                tap[dh][dw] = *(const float4*)(
                    xin + (size_t)((b << 10) | (hh << 5) | ww) * C_ + c0);
            else
                tap[dh][dw] = make_float4(0.f, 0.f, 0.f, 0.f);
        }
    }
    float4 wv[9];
#pragma unroll
    for (int k = 0; k < 9; k++)
        wv[k] = *(const float4*)(wt + k * C_ + c0);
    float4 bv = *(const float4*)(bias + c0);

#pragma unroll
    for (int row = 0; row < 2; row++) {
#pragma unroll
        for (int i = 0; i < 4; i++) {
            float4 acc = bv;
#pragma unroll
            for (int dh = 0; dh < 3; dh++)
#pragma unroll
                for (int dw = 0; dw < 3; dw++) {
                    float4 xv = tap[row + dh][i + dw];
                    float4 wk = wv[dh * 3 + dw];
                    acc.x += wk.x * xv.x; acc.y += wk.y * xv.y;
                    acc.z += wk.z * xv.z; acc.w += wk.w * xv.w;
                }
            float4 xr = tap[row + 1][i + 1];   // residual, always in-bounds
            acc.x += xr.x; acc.y += xr.y; acc.z += xr.z; acc.w += xr.w;
            *(float4*)(out + (size_t)((b << 10) | ((h0 + row) << 5) | (w0 + i)) * C_ + c0) = acc;
        }
    }
}

// ---------------- layernorm over C=768: fp32 in -> bf16 out -------------------
__global__ __launch_bounds__(256) void layernorm_bf(
    const float* __restrict__ xin, const float* __restrict__ g,
    const float* __restrict__ bb, ushort_t* __restrict__ out)
{
    int row = blockIdx.x;
    int t = threadIdx.x;
    const float* xr = xin + (size_t)row * C_;
    float x0 = xr[t], x1 = xr[t + 256], x2 = xr[t + 512];
    float s1 = x0 + x1 + x2;
    float s2 = x0 * x0 + x1 * x1 + x2 * x2;
#pragma unroll
    for (int o = 32; o > 0; o >>= 1) {
        s1 += __shfl_xor(s1, o);
        s2 += __shfl_xor(s2, o);
    }
    __shared__ float red[8];
    if ((t & 63) == 0) { red[(t >> 6) * 2] = s1; red[(t >> 6) * 2 + 1] = s2; }
    __syncthreads();
    s1 = red[0] + red[2] + red[4] + red[6];
    s2 = red[1] + red[3] + red[5] + red[7];
    float m = s1 * (1.0f / 768.0f);
    float var = s2 * (1.0f / 768.0f) - m * m;
    float inv = rsqrtf(var + 1e-5f);
    ushort_t* orow = out + (size_t)row * C_;
    orow[t]       = f2b((x0 - m) * inv * g[t]       + bb[t]);
    orow[t + 256] = f2b((x1 - m) * inv * g[t + 256] + bb[t + 256]);
    orow[t + 512] = f2b((x2 - m) * inv * g[t + 512] + bb[t + 512]);
}

// ---------------- bf16 GEMM: 128x128, ring-3 fully unrolled, counted vmcnt ----
// A: [M,K] bf16 row-major, W: [Nf,K] bf16 row-major => out = A @ W^T + bias
// EPI 0: bf16 out = acc+bias ; EPI 1: bf16 out = fast-gelu(acc+bias) ;
// EPI 2: fp32 out = acc+bias+resid(fp32)  (out may alias resid)
//
// R4 pipeline (verified) with the VALU overhead stripped:
//  - K-loop unrolled in groups of 3 tiles -> ring slot indices are literals
//    (no %3), LDS read/stage addresses precomputed once (ds offsets fold to
//    immediates), global pointers advance +96 elems per group.
//  - Schedule per sub: STAGE(next+2); ds_read cur; setprio(1) MFMA setprio(0);
//    vmcnt(4) (confirm next tile, never drain); s_barrier.  Tail: vmcnt(0).
//  - Requires NT = K/32 divisible by 3 and >= 6 (K=768 -> 24, K=3072 -> 96).
//  - T2 swizzle as verified in R4 (conflicts 0).
template <int EPI>
__global__ __launch_bounds__(256) void gemm_bt(
    const ushort_t* __restrict__ A, const ushort_t* __restrict__ W,
    const float* __restrict__ bias, const float* __restrict__ resid,
    void* __restrict__ outv, int M, int Nf, int K)
{
    __shared__ __align__(16) ushort_t ring[3][2][4096];  // 48 KB
    int t = threadIdx.x;
    int bm = blockIdx.x;   // M/128
    int bn = blockIdx.y;   // Nf/128
    int wave = t >> 6, lane = t & 63;
    int wm = (wave >> 1) * 64;
    int wn = (wave & 1) * 64;
    int row16 = lane & 15;
    int quad = lane >> 4;
    int qswz = (quad * 8) ^ (((row16 >> 1) & 3) * 8);  // read-side swizzle

    int r0 = wave * 16 + (lane >> 2);
    int r1 = (wave + 4) * 16 + (lane >> 2);
    int c8s = ((lane & 3) ^ ((lane >> 3) & 3)) * 8;
    const ushort_t* Ag0 = A + (size_t)(bm * 128 + r0) * K + c8s;
    const ushort_t* Ag1 = A + (size_t)(bm * 128 + r1) * K + c8s;
    const ushort_t* Wg0 = W + (size_t)(bn * 128 + r0) * K + c8s;
    const ushort_t* Wg1 = W + (size_t)(bn * 128 + r1) * K + c8s;

    // precomputed per-slot LDS stage destinations and read bases
    ushort_t *stA0[3], *stA1[3], *stB0[3], *stB1[3];
    const ushort_t *rdA[3], *rdB[3];
#pragma unroll
    for (int s = 0; s < 3; s++) {
        stA0[s] = &ring[s][0][0] + wave * 512;
        stA1[s] = &ring[s][0][0] + (wave + 4) * 512;
        stB0[s] = &ring[s][1][0] + wave * 512;
        stB1[s] = &ring[s][1][0] + (wave + 4) * 512;
        rdA[s]  = &ring[s][0][0] + (wm + row16) * 32 + qswz;
        rdB[s]  = &ring[s][1][0] + (wn + row16) * 32 + qswz;
    }

    v4f acc[4][4];
#pragma unroll
    for (int i = 0; i < 4; i++)
#pragma unroll
        for (int j = 0; j < 4; j++) acc[i][j] = (v4f){0.f, 0.f, 0.f, 0.f};

    auto STAGE = [&](int s, int off) {
        GLOAD_LDS16(Ag0 + off, stA0[s]);
        GLOAD_LDS16(Ag1 + off, stA1[s]);
        GLOAD_LDS16(Wg0 + off, stB0[s]);
        GLOAD_LDS16(Wg1 + off, stB1[s]);
    };
    auto COMPUTE = [&](int s) {
        v8bf af[4], bfr[4];
#pragma unroll
        for (int i = 0; i < 4; i++) af[i] = *(const v8bf*)(rdA[s] + i * 512);
#pragma unroll
        for (int j = 0; j < 4; j++) bfr[j] = *(const v8bf*)(rdB[s] + j * 512);
        __builtin_amdgcn_s_setprio(1);
#pragma unroll
        for (int i = 0; i < 4; i++)
#pragma unroll
            for (int j = 0; j < 4; j++)
                acc[i][j] = __builtin_amdgcn_mfma_f32_16x16x32_bf16(af[i], bfr[j], acc[i][j], 0, 0, 0);
        __builtin_amdgcn_s_setprio(0);
    };

    // prologue: tiles 0,1 -> slots 0,1; confirm tile 0
    STAGE(0, 0);
    STAGE(1, 32);
    asm volatile("s_waitcnt vmcnt(4)" ::: "memory");
    __builtin_amdgcn_s_barrier();

    // groups of 3 tiles; group g holds base offset g*96 in the pointers.
    // subs stage tiles 3g+2 (s2, +64), 3g+3 (s0, +96), 3g+4 (s1, +128).
    const int NG = K / 96;
    for (int g = 0; g < NG - 1; ++g) {
        STAGE(2, 64);  COMPUTE(0);
        asm volatile("s_waitcnt vmcnt(4)" ::: "memory");
        __builtin_amdgcn_s_barrier();
        STAGE(0, 96);  COMPUTE(1);
        asm volatile("s_waitcnt vmcnt(4)" ::: "memory");
        __builtin_amdgcn_s_barrier();
        STAGE(1, 128); COMPUTE(2);
        asm volatile("s_waitcnt vmcnt(4)" ::: "memory");
        __builtin_amdgcn_s_barrier();
        Ag0 += 96; Ag1 += 96; Wg0 += 96; Wg1 += 96;
    }
    // last group: tiles NT-3, NT-2, NT-1 (NT-1 staged here; no further stages)
    STAGE(2, 64); COMPUTE(0);
    asm volatile("s_waitcnt vmcnt(4)" ::: "memory");
    __builtin_amdgcn_s_barrier();
    COMPUTE(1);
    asm volatile("s_waitcnt vmcnt(0)" ::: "memory");
    __builtin_amdgcn_s_barrier();
    COMPUTE(2);

    // epilogue: hoisted bias, j-innermost (const address offsets)
    float bv[4];
#pragma unroll
    for (int j = 0; j < 4; j++) bv[j] = bias[bn * 128 + wn + j * 16 + row16];
    int col0 = bn * 128 + wn + row16;
#pragma unroll
    for (int i = 0; i < 4; i++) {
        int rowb = bm * 128 + wm + i * 16 + quad * 4;
#pragma unroll
        for (int r = 0; r < 4; r++) {
            size_t rb = (size_t)(rowb + r) * Nf + col0;
#pragma unroll
            for (int j = 0; j < 4; j++) {
                float v = acc[i][j][r] + bv[j];
                if (EPI == 1) {
                    // fast gelu: 0.5v(1+tanh(0.79788456(v+0.044715v^3)))
                    //          = v * sigmoid(2u); |err| vs erf-gelu < 3e-3
                    float u = v * (0.7978845608f + 0.0356774081f * v * v);
                    v = v / (1.0f + __expf(-2.0f * u));
                }
                if (EPI == 2) {
                    v += resid[rb + j * 16];
                    ((float*)outv)[rb + j * 16] = v;
                } else {
                    ((ushort_t*)outv)[rb + j * 16] = f2b(v);
                }
            }
        }
    }
}

// ---------------- channel attention (MFMA + reg-prefetch): P = softmax(qk/32) -
// (R8 known-good)
__global__ __launch_bounds__(256) void chan_attn(
    const ushort_t* __restrict__ qkv, ushort_t* __restrict__ P)
{
    __shared__ __align__(16) char smem[96 * 97 * 4];   // 37,248 B
    ushort_t* sQt = (ushort_t*)smem;                   // [96][72] bf16
    ushort_t* sKt = (ushort_t*)(smem + 13824);         // [96][72] bf16
    float* sS = (float*)smem;                          // [96][97] fp32 (after)
    int bg = blockIdx.x;
    int b = bg >> 3, g = bg & 7;
    int t = threadIdx.x;
    int wave = t >> 6, lane = t & 63;
    int wc = (wave >> 1) * 48, wd = (wave & 1) * 48;
    int row16 = lane & 15, quad = lane >> 4;

    int li0 = t * 3;
    int r_[3], sg_[3];
#pragma unroll
    for (int i = 0; i < 3; i++) { r_[i] = (li0 + i) / 12; sg_[i] = (li0 + i) % 12; }

    v4f acc[3][3];
#pragma unroll
    for (int i = 0; i < 3; i++)
#pragma unroll
        for (int j = 0; j < 3; j++) acc[i][j] = (v4f){0.f, 0.f, 0.f, 0.f};

    uint4 uq[3], uk[3];
#pragma unroll
    for (int i = 0; i < 3; i++) {
        const ushort_t* p = qkv + ((size_t)(b * N_ + r_[i]) * 3) * C_ + g * HD_ + sg_[i] * 8;
        uq[i] = *(const uint4*)p;
        uk[i] = *(const uint4*)(p + C_);
    }

    for (int n0 = 0; n0 < N_; n0 += 64) {
        uint4 nq[3] = {}, nk[3] = {};
        bool more = (n0 + 64 < N_);
        if (more) {
#pragma unroll
            for (int i = 0; i < 3; i++) {
                const ushort_t* p = qkv + ((size_t)(b * N_ + n0 + 64 + r_[i]) * 3) * C_ + g * HD_ + sg_[i] * 8;
                nq[i] = *(const uint4*)p;
                nk[i] = *(const uint4*)(p + C_);
            }
        }
        __syncthreads();                 // prev chunk's MFMA reads done
#pragma unroll
        for (int i = 0; i < 3; i++) {
            union { uint4 v; ushort_t s[8]; } a, bu;
            a.v = uq[i]; bu.v = uk[i];
#pragma unroll
            for (int k2 = 0; k2 < 8; k2++) {
                sQt[(sg_[i] * 8 + k2) * 72 + r_[i]] = a.s[k2];
                sKt[(sg_[i] * 8 + k2) * 72 + r_[i]] = bu.s[k2];
            }
        }
        __syncthreads();                 // transpose visible
#pragma unroll
        for (int kk = 0; kk < 64; kk += 32) {
            v8bf af[3], bf2[3];
#pragma unroll
            for (int i = 0; i < 3; i++)
                af[i] = *(const v8bf*)(sQt + (wc + i * 16 + row16) * 72 + kk + quad * 8);
#pragma unroll
            for (int j = 0; j < 3; j++)
                bf2[j] = *(const v8bf*)(sKt + (wd + j * 16 + row16) * 72 + kk + quad * 8);
#pragma unroll
            for (int i = 0; i < 3; i++)
#pragma unroll
                for (int j = 0; j < 3; j++)
                    acc[i][j] = __builtin_amdgcn_mfma_f32_16x16x32_bf16(af[i], bf2[j], acc[i][j], 0, 0, 0);
        }
        if (more) {
#pragma unroll
            for (int i = 0; i < 3; i++) { uq[i] = nq[i]; uk[i] = nk[i]; }
        }
    }
    __syncthreads();                     // last MFMA reads done; reuse LDS as sS
#pragma unroll
    for (int i = 0; i < 3; i++)
#pragma unroll
        for (int j = 0; j < 3; j++)
#pragma unroll
            for (int r = 0; r < 4; r++) {
                int c = wc + i * 16 + quad * 4 + r;    // MFMA C: row = quad*4+reg
                int d = wd + j * 16 + row16;           // col = lane&15
                sS[c * 97 + d] = acc[i][j][r] * 0.03125f;
            }
    __syncthreads();
    if (t < 96) {
        float mx = -1e30f;
        for (int d = 0; d < 96; d++) mx = fmaxf(mx, sS[t * 97 + d]);
        float sum = 0.f;
        for (int d = 0; d < 96; d++) sum += __expf(sS[t * 97 + d] - mx);
        float rs = 1.0f / sum;
        ushort_t* prow = P + (size_t)bg * 9216 + t * 96;
        for (int d = 0; d < 96; d++) prow[d] = f2b(__expf(sS[t * 97 + d] - mx) * rs);
    }
}

// ---------------- attention apply (MFMA): out[n,c] = sum_d P[c,d] V[n,d] -----
// (R6 known-good)
__global__ __launch_bounds__(256) void attn_av(
    const ushort_t* __restrict__ qkv, const ushort_t* __restrict__ P,
    ushort_t* __restrict__ out)
{
    __shared__ __align__(16) ushort_t sV[256 * 104];  // 53,248 B
    __shared__ __align__(16) ushort_t sP[96 * 104];   // 19,968 B
    int blk = blockIdx.x;                 // b_local*32 + g*4 + nch
    int nch = blk & 3, g = (blk >> 2) & 7, b = blk >> 5;
    int t = threadIdx.x;
    int n0 = nch * 256;
#pragma unroll
    for (int i = 0; i < 12; i++) {
        int li = t + i * 256;             // 0..3071
        int r = li / 12, sg = li % 12;
        size_t voff = ((size_t)(b * N_ + n0 + r) * 3 + 2) * C_ + g * HD_ + sg * 8;
        *(uint4*)(sV + r * 104 + sg * 8) = *(const uint4*)(qkv + voff);
    }
#pragma unroll
    for (int i = 0; i < 5; i++) {
        int li = t + i * 256;
        if (li < 1152) {
            int r = li / 12, sg = li % 12;
            *(uint4*)(sP + r * 104 + sg * 8) =
                *(const uint4*)(P + (size_t)(b * 8 + g) * 9216 + li * 8);
        }
    }
    __syncthreads();
    int wave = t >> 6, lane = t & 63;
    int wm = wave * 64;
    int row16 = lane & 15, quad = lane >> 4;
    v4f acc[4][6];
#pragma unroll
    for (int i = 0; i < 4; i++)
#pragma unroll
        for (int j = 0; j < 6; j++) acc[i][j] = (v4f){0.f, 0.f, 0.f, 0.f};
#pragma unroll
    for (int kk = 0; kk < 96; kk += 32) {
        v8bf af[4], bfr[6];
#pragma unroll
        for (int i = 0; i < 4; i++)
            af[i] = *(const v8bf*)(sV + (wm + i * 16 + row16) * 104 + kk + quad * 8);
#pragma unroll
        for (int j = 0; j < 6; j++)
            bfr[j] = *(const v8bf*)(sP + (j * 16 + row16) * 104 + kk + quad * 8);
#pragma unroll
        for (int i = 0; i < 4; i++)
#pragma unroll
            for (int j = 0; j < 6; j++)
                acc[i][j] = __builtin_amdgcn_mfma_f32_16x16x32_bf16(af[i], bfr[j], acc[i][j], 0, 0, 0);
    }
#pragma unroll
    for (int i = 0; i < 4; i++)
#pragma unroll
        for (int j = 0; j < 6; j++)
#pragma unroll
            for (int r = 0; r < 4; r++) {
                int n = n0 + wm + i * 16 + quad * 4 + r;
                int c = j * 16 + row16;
                out[(size_t)(b * N_ + n) * C_ + g * HD_ + c] = f2b(acc[i][j][r]);
            }
}

// -----------------------------------------------------------------------------
// bf16-internal chunked pipeline. Residual chain (x1/x2/x3/out) fp32.
extern "C" void kernel_launch(void* const* d_in, const int* in_sizes, int n_in,
                              void* d_out, int out_size, void* d_ws, size_t ws_size,
                              hipStream_t stream)
{
    const float* x      = (const float*)d_in[0];
    const float* dw1_w  = (const float*)d_in[3];
    const float* dw1_b  = (const float*)d_in[4];
    const float* ln1_g  = (const float*)d_in[5];
    const float* ln1_b  = (const float*)d_in[6];
    const float* qkv_w  = (const float*)d_in[7];
    const float* qkv_b  = (const float*)d_in[8];
    const float* proj_w = (const float*)d_in[9];
    const float* proj_b = (const float*)d_in[10];
    const float* dw2_w  = (const float*)d_in[11];
    const float* dw2_b  = (const float*)d_in[12];
    const float* ln2_g  = (const float*)d_in[13];
    const float* ln2_b  = (const float*)d_in[14];
    const float* fc1_w  = (const float*)d_in[15];
    const float* fc1_b  = (const float*)d_in[16];
    const float* fc2_w  = (const float*)d_in[17];
    const float* fc2_b  = (const float*)d_in[18];
    float* outp = (float*)d_out;    // holds x1, then x3, then final out

    char* ws = (char*)d_ws;
    // bf16 weight arena
    ushort_t* qkvW = (ushort_t*)ws;                          // 2304*768
    ushort_t* projW = qkvW + 2304 * 768;                     // 768*768
    ushort_t* fc1W = projW + 768 * 768;                      // 3072*768
    ushort_t* fc2W = fc1W + 3072 * 768;                      // 768*3072
    const size_t WB = (size_t)(2304*768 + 768*768 + 3072*768 + 768*3072) * 2; // 14,155,776
    // transposed dwconv weights [9][768] fp32
    float* wt1 = (float*)(ws + WB);
    float* wt2 = wt1 + 9 * C_;
    const size_t WTB = 2 * 9 * C_ * sizeof(float);           // 55,296

    size_t CB = 32;
    while (CB > 1 && WB + WTB + CB * 12730368ull > ws_size) CB >>= 1;
    const size_t R = CB * 1024;
    char* act = ws + WB + WTB;
    ushort_t* L  = (ushort_t*)act;                           // [R,768] bf16
    ushort_t* Ab = (ushort_t*)(act + R * C_ * 2);            // [R,768] bf16
    float*    X2 = (float*)(act + 2 * R * C_ * 2);           // [R,768] fp32
    ushort_t* P  = (ushort_t*)(act + 2 * R * C_ * 2 + R * C_ * 4);
    ushort_t* D  = (ushort_t*)(act + 2 * R * C_ * 2 + R * C_ * 4 + CB * 147456);

    // 0. weight conversion fp32 -> bf16 (1 launch) ; dwconv transpose (1)
    cvt_all<<<6912, 256, 0, stream>>>(qkv_w, proj_w, fc1_w, fc2_w, qkvW);
    transpose_w2<<<54, 256, 0, stream>>>(dw1_w, dw2_w, wt1, wt2);

    // 1. x1 = x + dwconv1(x) -> d_out  (full, fp32)
    dwconv_add<<<32 * 16 * 6, 256, 0, stream>>>(x, wt1, dw1_b, outp);

    const int nchunk = (int)(32 / CB);
    for (int c = 0; c < nchunk; c++) {
        float* xc = outp + (size_t)c * R * C_;   // x1 chunk, later x3 chunk
        // ln1 -> L (bf16)
        layernorm_bf<<<(int)R, 256, 0, stream>>>(xc, ln1_g, ln1_b, L);
        // qkv = L @ qkvW^T + b -> D (bf16)
        gemm_bt<0><<<dim3((int)R / 128, 2304 / 128), 256, 0, stream>>>(
            L, qkvW, qkv_b, nullptr, D, (int)R, 2304, C_);
        // P = softmax(q^T k / 32)  (MFMA, reg-prefetch)
        chan_attn<<<(int)CB * 8, 256, 0, stream>>>(D, P);
        // A = P @ v (MFMA)
        attn_av<<<(int)CB * 32, 256, 0, stream>>>(D, P, Ab);
        // x2 = x1 + A @ projW^T + b -> X2 (fp32)
        gemm_bt<2><<<dim3((int)R / 128, C_ / 128), 256, 0, stream>>>(
            Ab, projW, proj_b, xc, X2, (int)R, C_, C_);
        // x3 = x2 + dwconv2(x2) -> d_out chunk (fp32)
        dwconv_add<<<(int)(R / 1024) * 16 * 6, 256, 0, stream>>>(X2, wt2, dw2_b, xc);
        // ln2 -> L (bf16)
        layernorm_bf<<<(int)R, 256, 0, stream>>>(xc, ln2_g, ln2_b, L);
        // h = gelu(L @ fc1W^T + b) -> D (bf16)
        gemm_bt<1><<<dim3((int)R / 128, CH_ / 128), 256, 0, stream>>>(
            L, fc1W, fc1_b, nullptr, D, (int)R, CH_, C_);
        // out = x3 + h @ fc2W^T + b -> d_out chunk (fp32, alias-safe)
        gemm_bt<2><<<dim3((int)R / 128, C_ / 128), 256, 0, stream>>>(
            D, fc2W, fc2_b, xc, xc, (int)R, C_, CH_);
    }
}